// Round 2
// baseline (781.631 us; speedup 1.0000x reference)
//
#include <hip/hip_runtime.h>
#include <hip/hip_bf16.h>
#include <stdint.h>

// Problem: out[b,s,o] = sum_i x[b,s,i] * W[o,i],  W = (V * (s*mask)) @ U^T
// Factored: Y = (x @ U) * (s*mask)  [16384, 512];  out = Y @ V^T  [16384, 4096]
// M = 8*2048 = 16384, IN_F = 4096, OUT_F = 4096, KMAX = 512.
//
// R2 = R1 resubmit (R1 failed at the container level, no kernel verdict):
//  - prep_x: X f32 -> bf16 once (streaming); Xb goes to workspace when
//    ws_size permits, else parks in d_out (dead until gemm2 writes it).
//  - both GEMMs: 2-phase pipeline — double-buffered LDS, stage tile t+1
//    (async global_load_lds) BEFORE computing tile t, ONE __syncthreads
//    per K-tile (its vmcnt(0) drain lands the prefetch).
//  - #pragma unroll 1 on the K-tile loop (defensive: no unroll explosion).

typedef __attribute__((ext_vector_type(8))) short short8;   // 8 bf16 = 4 VGPRs (MFMA A/B frag)
typedef __attribute__((ext_vector_type(4))) float f32x4;    // MFMA C/D frag
typedef __attribute__((ext_vector_type(4))) unsigned int uint4v;

// ---- helpers ----------------------------------------------------------------

// round-to-nearest-even f32 -> bf16 bits
__device__ __forceinline__ unsigned short f2bf_rne(float f) {
    unsigned int u = __builtin_bit_cast(unsigned int, f);
    unsigned int r = u + 0x7fffu + ((u >> 16) & 1u);
    return (unsigned short)(r >> 16);
}

// pack two f32 -> two bf16 (round-half-up; error negligible vs tolerance)
__device__ __forceinline__ unsigned int pk2bf(float a, float b) {
    unsigned int ua = __builtin_bit_cast(unsigned int, a);
    unsigned int ub = __builtin_bit_cast(unsigned int, b);
    ua = (ua + 0x8000u) >> 16;
    ub = (ub + 0x8000u) & 0xffff0000u;
    return ua | ub;
}

// async global->LDS, 16 bytes/lane; LDS dest must be wave-uniform base (+lane*16 implicit)
__device__ __forceinline__ void async_load16(const void* g, void* l) {
    __builtin_amdgcn_global_load_lds(
        (const __attribute__((address_space(1))) unsigned int*)g,
        (__attribute__((address_space(3))) unsigned int*)l,
        16, 0, 0);
}

// ---- prep kernels -----------------------------------------------------------

// Ut[n][k] = bf16( U[k][n] * s[n] * mask[n] ),  U: [4096,512] f32 -> Ut: [512,4096] bf16
__global__ void prep_u(const float* __restrict__ U, const float* __restrict__ S,
                       const int* __restrict__ Mask, unsigned short* __restrict__ Ut) {
    __shared__ float t[32][33];
    const int tx = threadIdx.x, ty = threadIdx.y;       // (32, 8)
    const int n0 = blockIdx.x * 32, k0 = blockIdx.y * 32;
#pragma unroll
    for (int i = 0; i < 4; ++i)
        t[ty + i * 8][tx] = U[(size_t)(k0 + ty + i * 8) * 512 + n0 + tx];
    __syncthreads();
#pragma unroll
    for (int i = 0; i < 4; ++i) {
        int n = n0 + ty + i * 8;
        float sm = S[n] * (Mask[n] != 0 ? 1.0f : 0.0f);
        Ut[(size_t)n * 4096 + k0 + tx] = f2bf_rne(t[tx][ty + i * 8] * sm);
    }
}

// Vb = bf16(V), elementwise, 4096*512 = 2M elems, 4/thread
__global__ void prep_v(const float* __restrict__ V, unsigned short* __restrict__ Vb) {
    int i = blockIdx.x * blockDim.x + threadIdx.x;      // 0..524287
    float4 f = ((const float4*)V)[i];
    ushort4 o;
    o.x = f2bf_rne(f.x); o.y = f2bf_rne(f.y);
    o.z = f2bf_rne(f.z); o.w = f2bf_rne(f.w);
    ((ushort4*)Vb)[i] = o;
}

// Xb = bf16(X), 16384*4096 = 67.1M elems, 8/thread (2x float4 -> 1x 16B store)
__global__ __launch_bounds__(256) void prep_x(const float* __restrict__ X,
                                              unsigned short* __restrict__ Xb) {
    size_t i = (size_t)blockIdx.x * 256 + threadIdx.x;  // 8,388,608 threads
    const float4* src = (const float4*)X;
    float4 f0 = src[2 * i];
    float4 f1 = src[2 * i + 1];
    uint4v p;
    p.x = pk2bf(f0.x, f0.y); p.y = pk2bf(f0.z, f0.w);
    p.z = pk2bf(f1.x, f1.y); p.w = pk2bf(f1.z, f1.w);
    ((uint4v*)Xb)[i] = p;
}

// ---- GEMM: C[128x128 tile] = A[M x K] @ B[N x K]^T, bf16 in, 2-phase pipeline
// 256 threads (4 waves, 64x64/wave), BK=64, mfma 16x16x32 bf16.
// LDS chunk index c = kc*128 + row  (kc = k/8 within tile), 16B chunks.
// K is also the row stride of A and B. OUT_BF16 selects Y(bf16) vs Out(f32).
template <int K, bool OUT_BF16, int LDOUT>
__global__ __launch_bounds__(256, 2)
void gemm_bt(const unsigned short* __restrict__ A, const unsigned short* __restrict__ B,
             void* __restrict__ Out) {
    const int tid  = threadIdx.x;
    const int lane = tid & 63;
    const int w    = tid >> 6;
    const int ln   = lane & 15;
    const int quad = lane >> 4;
    const int m0 = blockIdx.y * 128;
    const int n0 = blockIdx.x * 128;
    const int wm = (w >> 1) * 64;
    const int wn = (w & 1) * 64;

    __shared__ short8 As[2][1024];   // 2 x 16 KiB
    __shared__ short8 Bs[2][1024];   // 2 x 16 KiB

    f32x4 acc[4][4] = {};

    constexpr int NT = K / 64;

    auto stage = [&](int buf, int kt) {
#pragma unroll
        for (int i = 0; i < 4; ++i) {
            int cbase = i * 256 + w * 64;               // wave-uniform
            int c = cbase + lane;
            int kc = c >> 7, r = c & 127;
            async_load16(A + (size_t)(m0 + r) * K + kt + kc * 8, (void*)&As[buf][cbase]);
            async_load16(B + (size_t)(n0 + r) * K + kt + kc * 8, (void*)&Bs[buf][cbase]);
        }
    };

    stage(0, 0);
    int cur = 0;
#pragma unroll 1
    for (int t = 0; t < NT; ++t) {
        // drains vmcnt(0) (lands prefetch into buf[cur]) + lgkm, then barrier
        __syncthreads();
        if (t + 1 < NT) stage(cur ^ 1, (t + 1) * 64);   // async, overlaps MFMAs below
#pragma unroll
        for (int ks = 0; ks < 2; ++ks) {
            const int kc = ks * 4 + quad;
            short8 a[4], b[4];
#pragma unroll
            for (int tt = 0; tt < 4; ++tt) {
                a[tt] = As[cur][kc * 128 + wm + tt * 16 + ln];
                b[tt] = Bs[cur][kc * 128 + wn + tt * 16 + ln];
            }
#pragma unroll
            for (int mt = 0; mt < 4; ++mt)
#pragma unroll
                for (int nt = 0; nt < 4; ++nt)
                    acc[mt][nt] = __builtin_amdgcn_mfma_f32_16x16x32_bf16(
                        a[mt], b[nt], acc[mt][nt], 0, 0, 0);
        }
        cur ^= 1;
    }

    // epilogue: C/D layout col = ln, row = quad*4 + r (m89-verified)
#pragma unroll
    for (int mt = 0; mt < 4; ++mt)
#pragma unroll
        for (int nt = 0; nt < 4; ++nt) {
            int col = n0 + wn + nt * 16 + ln;
#pragma unroll
            for (int r = 0; r < 4; ++r) {
                int row = m0 + wm + mt * 16 + quad * 4 + r;
                if constexpr (OUT_BF16)
                    ((unsigned short*)Out)[(size_t)row * LDOUT + col] = f2bf_rne(acc[mt][nt][r]);
                else
                    ((float*)Out)[(size_t)row * LDOUT + col] = acc[mt][nt][r];
            }
        }
}

// ---- launch -----------------------------------------------------------------

extern "C" void kernel_launch(void* const* d_in, const int* in_sizes, int n_in,
                              void* d_out, int out_size, void* d_ws, size_t ws_size,
                              hipStream_t stream) {
    const float* X    = (const float*)d_in[0];   // [8,2048,4096]
    const float* U    = (const float*)d_in[1];   // [4096,512]
    const float* V    = (const float*)d_in[2];   // [4096,512]
    const float* S    = (const float*)d_in[3];   // [512]
    const int*   Mask = (const int*)d_in[4];     // [512]

    char* ws = (char*)d_ws;
    const size_t UT_B = (size_t)512 * 4096 * 2;          // 4 MiB
    const size_t VB_B = (size_t)512 * 4096 * 2;          // 4 MiB
    const size_t YB_B = (size_t)16384 * 512 * 2;         // 16 MiB
    const size_t XB_B = (size_t)16384 * 4096 * 2;        // 128 MiB

    unsigned short* Ut = (unsigned short*)ws;
    unsigned short* Vb = (unsigned short*)(ws + UT_B);
    unsigned short* Yb = (unsigned short*)(ws + UT_B + VB_B);
    float* Out = (float*)d_out;

    // Xb: prefer workspace; else park in d_out (dead until gemm2 overwrites
    // the whole output buffer; stream-ordered, safe).
    unsigned short* Xb;
    if (ws_size >= UT_B + VB_B + YB_B + XB_B)
        Xb = (unsigned short*)(ws + UT_B + VB_B + YB_B);
    else
        Xb = (unsigned short*)d_out;

    prep_u<<<dim3(16, 128), dim3(32, 8), 0, stream>>>(U, S, Mask, Ut);
    prep_v<<<dim3(1024), dim3(512), 0, stream>>>(V, Vb);
    prep_x<<<dim3(32768), dim3(256), 0, stream>>>(X, Xb);
    gemm_bt<4096, true, 512><<<dim3(4, 128), dim3(256), 0, stream>>>(Xb, Ut, Yb);
    gemm_bt<512, false, 4096><<<dim3(32, 128), dim3(256), 0, stream>>>(Yb, Vb, Out);
}